// Round 15
// baseline (10511.915 us; speedup 1.0000x reference)
//
#include <hip/hip_runtime.h>
#include <hip/hip_bf16.h>
#include <math.h>

typedef __hip_bfloat16 bf16;

#define G_GRAPHS 256
#define EPG 2048
#define E_TOT 524288
#define HF 256
#define FIN 128

__device__ __forceinline__ float b2f(bf16 v) { return __bfloat162float(v); }

// load float-typed input element, honoring probed storage dtype
__device__ __forceinline__ float ldf(const void* p, size_t idx, int f32) {
    return f32 ? ((const float*)p)[idx] : b2f(((const bf16*)p)[idx]);
}

// ---------------------------------------------------------------------------
// One block per graph; full pipeline, fp32 math, float32 output.
// Input dtype (fp32 vs bf16) and edge layout ((2,E) vs (E,2)) probed on-device.
// ---------------------------------------------------------------------------
__global__ __launch_bounds__(256, 1)
void gnn_mono(const void* __restrict__ x, const int* __restrict__ ei,
              const void* __restrict__ gw0, const void* __restrict__ gb0,
              const void* __restrict__ gw1, const void* __restrict__ gb1,
              const void* __restrict__ gw2, const void* __restrict__ gb2,
              const void* __restrict__ pw0, const void* __restrict__ pw1,
              const void* __restrict__ pw2,
              const void* __restrict__ l1w, const void* __restrict__ l1b,
              const void* __restrict__ l2w, const void* __restrict__ l2b,
              const void* __restrict__ l3w, const void* __restrict__ l3b,
              float* __restrict__ out, float* __restrict__ ws) {
    const int g = blockIdx.x;
    const int t = threadIdx.x;

    float* P = ws + (size_t)g * HF * 256;                               // slab A
    float* Q = ws + (size_t)G_GRAPHS * HF * 256 + (size_t)g * HF * 256; // slab B

    __shared__ int   eb[EPG];
    __shared__ int   slots[EPG];
    __shared__ int   curID[256];
    __shared__ int   cntL[256];
    __shared__ int   startL[256];
    __shared__ float degF[256];
    __shared__ float dinv[256];
    __shared__ float sa[256];
    __shared__ float ss[256];
    __shared__ int   si_[256];
    __shared__ float scoreV[256];
    __shared__ int   kept[128];
    __shared__ int   rankOf[256];
    __shared__ float row[512];
    __shared__ int   flagF32, flagPlanar;

    // ---- PROBES (thread 0; correct this time) ----
    if (t == 0) {
        const unsigned int* xw = (const unsigned int*)x;
        int hit = 0;
        for (int i = 0; i < 64; ++i) {
            unsigned int lo = xw[i] & 0xffffu;
            unsigned int ex = (lo >> 7) & 0xffu;        // bf16 exponent field
            if (ex >= 0x75u && ex <= 0x87u) ++hit;      // N(0,1) bf16: ~always
        }
        flagF32 = (hit >= 32) ? 0 : 1;    // fp32 mantissa bits hit ~7%
        flagPlanar = (ei[E_TOT] < 512) ? 1 : 0;
    }
    __syncthreads();
    const int F32 = flagF32;
    const int PL  = flagPlanar;

    // ---- load edges (original-local endpoints) ----
    for (int e = t; e < EPG; e += 256) {
        int u, v;
        size_t idx = (size_t)g * EPG + e;
        if (PL) { u = ei[idx]; v = ei[E_TOT + idx]; }
        else    { u = ei[2 * idx]; v = ei[2 * idx + 1]; }
        eb[e] = ((u - g * 256) << 8) | (v - g * 256);
    }
    curID[t] = t;

    float accMx = 0.f, accMn = 0.f;

    const void* GW[3] = {gw0, gw1, gw2};
    const void* GB[3] = {gb0, gb1, gb2};
    const void* PW[3] = {pw0, pw1, pw2};
    const int kk[3] = {128, 64, 32};

    int npg = 256;
    __syncthreads();

    for (int s = 0; s < 3; ++s) {
        const int knext = kk[s];

        // ---- 1) h = X @ W (fp32) ----
        {
            const void* Wp = GW[s];
            const int K = (s == 0) ? FIN : HF;
            for (int n = 0; n < npg; ++n) {
                if (s == 0) {
                    if (t < FIN) sa[t] = ldf(x, (size_t)(g * 256 + n) * FIN + t, F32);
                } else {
                    sa[t] = P[(size_t)n * HF + t];
                }
                __syncthreads();
                float a = 0.f;
                for (int k2 = 0; k2 < K; ++k2)
                    a += sa[k2] * ldf(Wp, (size_t)k2 * HF + t, F32);
                Q[(size_t)n * HF + t] = a;
                __syncthreads();
            }
        }

        // ---- 2) deg + CSR by dst (ascending edge order) ----
        cntL[t] = 0;
        __syncthreads();
        for (int e = t; e < EPG; e += 256) {
            int p = eb[e];
            int cu = curID[p >> 8], cv = curID[p & 255];
            if (cu >= 0 && cv >= 0) atomicAdd(&cntL[cv], 1);
        }
        __syncthreads();
        if (t == 0) {
            int run = 0;
            for (int i = 0; i < npg; ++i) { startL[i] = run; run += cntL[i]; }
        }
        __syncthreads();
        if (t < npg) {
            float d = (float)cntL[t] + 1.0f;
            degF[t] = d;
            dinv[t] = 1.0f / sqrtf(d);
            int c = startL[t];
            for (int e = 0; e < EPG; ++e) {
                int p = eb[e];
                int cu = curID[p >> 8], cv = curID[p & 255];
                if (cu >= 0 && cv >= 0 && cv == t) slots[c++] = e;
            }
        }
        __syncthreads();

        // ---- 3) conv: P = relu(agg + h/deg + b) ----
        {
            const float bb = ldf(GB[s], t, F32);
            for (int n = 0; n < npg; ++n) {
                float acc = 0.f;
                const int s0 = startL[n], s1 = s0 + cntL[n];
                for (int j = s0; j < s1; ++j) {
                    int p = eb[slots[j]];
                    int scur = curID[p >> 8];
                    acc += dinv[scur] * Q[(size_t)scur * HF + t];
                }
                float v = acc * dinv[n] + Q[(size_t)n * HF + t] / degF[n] + bb;
                P[(size_t)n * HF + t] = fmaxf(v, 0.f);
            }
        }
        __syncthreads();

        // ---- 4) scores: tanhf((x.w)/||w||) (1 wave per node group) ----
        {
            const void* pwp = PW[s];
            const int lane = t & 63, wv = t >> 6;
            float s2p = 0.f;
            for (int j = 0; j < 4; ++j) {
                float w = ldf(pwp, lane + 64 * j, F32);
                s2p += w * w;
            }
            for (int off = 32; off; off >>= 1) s2p += __shfl_down(s2p, off, 64);
            s2p = __shfl(s2p, 0, 64);
            const float nw = sqrtf(s2p);
            for (int n = wv; n < npg; n += 4) {
                float pr = 0.f;
                for (int j = 0; j < 4; ++j) {
                    int f = lane + 64 * j;
                    pr += P[(size_t)n * HF + f] * ldf(pwp, f, F32);
                }
                for (int off = 32; off; off >>= 1) pr += __shfl_down(pr, off, 64);
                if (lane == 0) scoreV[n] = tanhf(pr / nw);
            }
        }
        __syncthreads();

        // ---- 5) top-k: bitonic (score desc, idx asc) ----
        if (t < npg) { ss[t] = scoreV[t]; si_[t] = t; }
        else         { ss[t] = -INFINITY; si_[t] = 0x7FFFFFFF; }
        for (int size = 2; size <= 256; size <<= 1) {
            for (int stride = size >> 1; stride > 0; stride >>= 1) {
                __syncthreads();
                int i = t, j = t ^ stride;
                if (j > i) {
                    float a = ss[i], b = ss[j];
                    int ia = si_[i], ib = si_[j];
                    bool inOrder = (a > b) || (a == b && ia < ib);
                    bool desc = ((i & size) == 0);
                    if (desc ? !inOrder : inOrder) {
                        ss[i] = b; ss[j] = a; si_[i] = ib; si_[j] = ia;
                    }
                }
            }
        }
        __syncthreads();
        if (t < knext) kept[t] = si_[t];
        __syncthreads();

        // ---- 6) pool + readout ----
        {
            float mx = -INFINITY, sm = 0.f;
            for (int n = 0; n < knext; ++n) {
                int o = kept[n];
                float vv = P[(size_t)o * HF + t] * scoreV[o];
                Q[(size_t)n * HF + t] = vv;
                mx = fmaxf(mx, vv);
                sm += vv;
            }
            accMx += mx;
            accMn += sm / (float)knext;
        }

        // ---- 7) update original->current map ----
        rankOf[t] = -1;
        __syncthreads();
        if (t < knext) rankOf[kept[t]] = t;
        __syncthreads();
        {
            int c = curID[t];
            curID[t] = (c >= 0) ? rankOf[c] : -1;
        }
        __syncthreads();

        { float* tmp = P; P = Q; Q = tmp; }
        npg = knext;
    }

    // ---------------- MLP head (fp32) ----------------
    row[t] = accMx;
    row[256 + t] = accMn;
    __syncthreads();
    {
        float a = ldf(l1b, t, F32);
        for (int j = 0; j < 512; ++j) a += row[j] * ldf(l1w, (size_t)j * 256 + t, F32);
        scoreV[t] = fmaxf(a, 0.f);
    }
    __syncthreads();
    if (t < 128) {
        float a2 = ldf(l2b, t, F32);
        for (int j = 0; j < 256; ++j) a2 += scoreV[j] * ldf(l2w, (size_t)j * 128 + t, F32);
        sa[t] = fmaxf(a2, 0.f);
    }
    __syncthreads();
    if (t == 0) {
        float l0 = ldf(l3b, 0, F32), l1 = ldf(l3b, 1, F32);
        for (int j = 0; j < 128; ++j) {
            float h = sa[j];
            l0 += h * ldf(l3w, j * 2 + 0, F32);
            l1 += h * ldf(l3w, j * 2 + 1, F32);
        }
        float m = fmaxf(l0, l1);
        float lse = m + logf(expf(l0 - m) + expf(l1 - m));
        out[g * 2 + 0] = l0 - lse;      // float32 output
        out[g * 2 + 1] = l1 - lse;
    }
}

// ---------------------------------------------------------------------------
extern "C" void kernel_launch(void* const* d_in, const int* in_sizes, int n_in,
                              void* d_out, int out_size, void* d_ws, size_t ws_size,
                              hipStream_t stream) {
    gnn_mono<<<G_GRAPHS, 256, 0, stream>>>(
        d_in[0], (const int*)d_in[1],
        d_in[3], d_in[4], d_in[5], d_in[6], d_in[7], d_in[8],
        d_in[9], d_in[10], d_in[11],
        d_in[12], d_in[13], d_in[14], d_in[15], d_in[16], d_in[17],
        (float*)d_out, (float*)d_ws);
}

// Round 16
// 1045.051 us; speedup vs baseline: 10.0588x; 10.0588x over previous
//
#include <hip/hip_runtime.h>
#include <hip/hip_bf16.h>
#include <math.h>

#define G_GRAPHS 256
#define EPG 2048
#define E_TOT 524288
#define HF 256
#define FIN 128

// ============================================================================
// Parallel pipeline kernels
// ============================================================================

__global__ void init_cur(int* __restrict__ cur) {
    int i = blockIdx.x * blockDim.x + threadIdx.x;
    if (i < G_GRAPHS * 256) cur[i] = i & 255;
}

// ---------------------------------------------------------------------------
// C[N x 256] = A[N x K] @ W[K x 256], fp32, k-ascending accumulation.
// Block: 256 thr -> 64x64 C-tile, 4x4 per thread. grid = (N/64, 4).
// ---------------------------------------------------------------------------
template <int K>
__global__ __launch_bounds__(256)
void gemm_t4(const float* __restrict__ A, const float* __restrict__ W,
             float* __restrict__ C) {
    __shared__ float As[64][68];   // [kk][row]
    __shared__ float Ws[64][68];   // [kk][col]
    const int tid = threadIdx.x;
    const int tx = tid & 15;
    const int ty = tid >> 4;
    const int r0 = blockIdx.x * 64;
    const int c0 = blockIdx.y * 64;
    float acc[4][4] = {{0.f}};
    for (int k0 = 0; k0 < K; k0 += 64) {
        for (int i = tid; i < 4096; i += 256) {
            int r = i >> 6, kk = i & 63;
            As[kk][r] = A[(size_t)(r0 + r) * K + (k0 + kk)];
        }
        for (int i = tid; i < 4096; i += 256) {
            int kk = i >> 6, c = i & 63;
            Ws[kk][c] = W[(size_t)(k0 + kk) * 256 + (c0 + c)];
        }
        __syncthreads();
#pragma unroll 8
        for (int kk = 0; kk < 64; ++kk) {
            float4 av = *(const float4*)&As[kk][ty * 4];
            float4 wv = *(const float4*)&Ws[kk][tx * 4];
            acc[0][0] += av.x * wv.x; acc[0][1] += av.x * wv.y;
            acc[0][2] += av.x * wv.z; acc[0][3] += av.x * wv.w;
            acc[1][0] += av.y * wv.x; acc[1][1] += av.y * wv.y;
            acc[1][2] += av.y * wv.z; acc[1][3] += av.y * wv.w;
            acc[2][0] += av.z * wv.x; acc[2][1] += av.z * wv.y;
            acc[2][2] += av.z * wv.z; acc[2][3] += av.z * wv.w;
            acc[3][0] += av.w * wv.x; acc[3][1] += av.w * wv.y;
            acc[3][2] += av.w * wv.z; acc[3][3] += av.w * wv.w;
        }
        __syncthreads();
    }
#pragma unroll
    for (int i = 0; i < 4; ++i) {
        float4 v = make_float4(acc[i][0], acc[i][1], acc[i][2], acc[i][3]);
        *(float4*)&C[(size_t)(r0 + ty * 4 + i) * 256 + c0 + tx * 4] = v;
    }
}

// ---------------------------------------------------------------------------
// Per-graph CSR by dst (ascending edge order), deg, dinv. grid G, block 256.
// slotsS stores GLOBAL src current-node id per in-edge.
// ---------------------------------------------------------------------------
__global__ __launch_bounds__(256)
void csr_build(const int* __restrict__ ei, const int* __restrict__ cur, int npg,
               int* __restrict__ degS, float* __restrict__ dinvS,
               int* __restrict__ startsS, int* __restrict__ slotsS) {
    __shared__ int cul[EPG];
    __shared__ int cvl[EPG];
    __shared__ int cnt[256];
    __shared__ int st[256];
    const int g = blockIdx.x;
    const int t = threadIdx.x;
    if (t < npg) cnt[t] = 0;
    __syncthreads();
    for (int e = t; e < EPG; e += 256) {
        size_t idx = (size_t)g * EPG + e;
        int ul = ei[idx] - g * 256;
        int vl = ei[E_TOT + idx] - g * 256;
        int cu = cur[g * 256 + ul];
        int cv = cur[g * 256 + vl];
        if (cu >= 0 && cv >= 0) { atomicAdd(&cnt[cv], 1); }
        else cv = -1;
        cul[e] = cu;
        cvl[e] = cv;
    }
    __syncthreads();
    if (t == 0) {
        int run = 0;
        for (int i = 0; i < npg; ++i) { st[i] = run; run += cnt[i]; }
    }
    __syncthreads();
    if (t < npg) {
        int node = g * npg + t;
        degS[node] = cnt[t] + 1;
        dinvS[node] = 1.0f / sqrtf((float)(cnt[t] + 1));
        int base = g * EPG + st[t];
        startsS[node] = base;
        int c = base;
        for (int e = 0; e < EPG; ++e)
            if (cvl[e] == t) slotsS[c++] = g * npg + cul[e];  // ascending e
    }
}

// ---------------------------------------------------------------------------
// conv + relu + pool score. Block = current node, 256 thr = feats.
// Score reduction replicates the monolith's exact wave-0 butterfly order.
// ---------------------------------------------------------------------------
__global__ __launch_bounds__(256)
void agg_score(const int* __restrict__ degS, const float* __restrict__ dinvS,
               const int* __restrict__ startsS, const int* __restrict__ slotsS,
               const float* __restrict__ HL, float* __restrict__ H2,
               const float* __restrict__ bias, const float* __restrict__ pw,
               float* __restrict__ score) {
    __shared__ float vrow[256];
    const int node = blockIdx.x;
    const int t = threadIdx.x;
    const int cntE = degS[node] - 1;
    const float degF = (float)degS[node];
    const float dn = dinvS[node];
    const int s0 = startsS[node];
    float acc = 0.f;
    for (int j = 0; j < cntE; ++j) {
        int srcg = slotsS[s0 + j];
        acc += dinvS[srcg] * HL[(size_t)srcg * 256 + t];
    }
    float v = acc * dn + HL[(size_t)node * 256 + t] / degF + bias[t];
    v = fmaxf(v, 0.f);
    H2[(size_t)node * 256 + t] = v;
    vrow[t] = v;
    __syncthreads();
    if (t < 64) {
        const int lane = t;
        float pr = 0.f, s2p = 0.f;
        for (int j = 0; j < 4; ++j) {
            int f = lane + 64 * j;
            float w = pw[f];
            pr += vrow[f] * w;
            s2p += w * w;
        }
        for (int off = 32; off; off >>= 1) {
            pr += __shfl_down(pr, off, 64);
            s2p += __shfl_down(s2p, off, 64);
        }
        s2p = __shfl(s2p, 0, 64);
        if (lane == 0) score[node] = tanhf(pr / sqrtf(s2p));
    }
}

// ---------------------------------------------------------------------------
// top-k per graph (bitonic, score desc / idx asc) + cur update.
// ---------------------------------------------------------------------------
__global__ __launch_bounds__(256)
void topk_cur(const float* __restrict__ score, int npg, int k,
              int* __restrict__ kept, int* __restrict__ cur) {
    __shared__ float ss[256];
    __shared__ int si_[256];
    __shared__ int rankOf[256];
    const int g = blockIdx.x;
    const int t = threadIdx.x;
    if (t < npg) { ss[t] = score[g * npg + t]; si_[t] = t; }
    else         { ss[t] = -INFINITY; si_[t] = 0x7FFFFFFF; }
    for (int size = 2; size <= 256; size <<= 1) {
        for (int stride = size >> 1; stride > 0; stride >>= 1) {
            __syncthreads();
            int i = t, j = t ^ stride;
            if (j > i) {
                float a = ss[i], b = ss[j];
                int ia = si_[i], ib = si_[j];
                bool inOrder = (a > b) || (a == b && ia < ib);
                bool desc = ((i & size) == 0);
                if (desc ? !inOrder : inOrder) {
                    ss[i] = b; ss[j] = a; si_[i] = ib; si_[j] = ia;
                }
            }
        }
    }
    __syncthreads();
    rankOf[t] = -1;
    __syncthreads();
    if (t < k) {
        kept[g * k + t] = g * npg + si_[t];
        rankOf[si_[t]] = t;
    }
    __syncthreads();
    {
        int v = g * 256 + t;
        int c = cur[v];
        cur[v] = (c >= 0) ? rankOf[c] : -1;
    }
}

// new_x[j,:] = H2[kept[j],:] * score[kept[j]]
__global__ __launch_bounds__(256)
void pool_gather(const int* __restrict__ kept, const float* __restrict__ score,
                 const float* __restrict__ H2, float* __restrict__ OUT) {
    const int j = blockIdx.x;
    const int t = threadIdx.x;
    const int o = kept[j];
    OUT[(size_t)j * 256 + t] = H2[(size_t)o * 256 + t] * score[o];
}

// outacc[g] {=, +=} [segment_max ; segment_mean]
__global__ __launch_bounds__(256)
void readout(const float* __restrict__ X, int k, float* __restrict__ outacc,
             int first) {
    const int g = blockIdx.x;
    const int t = threadIdx.x;
    const float* base = X + (size_t)g * k * 256 + t;
    float mx = -INFINITY, sm = 0.f;
    for (int n = 0; n < k; ++n) {
        float vv = base[(size_t)n * 256];
        mx = fmaxf(mx, vv);
        sm += vv;
    }
    float mean = sm / (float)k;
    if (first) {
        outacc[g * 512 + t] = mx;
        outacc[g * 512 + 256 + t] = mean;
    } else {
        outacc[g * 512 + t] += mx;
        outacc[g * 512 + 256 + t] += mean;
    }
}

__global__ __launch_bounds__(256)
void mlp_head(const float* __restrict__ outacc,
              const float* __restrict__ l1w, const float* __restrict__ l1b,
              const float* __restrict__ l2w, const float* __restrict__ l2b,
              const float* __restrict__ l3w, const float* __restrict__ l3b,
              float* __restrict__ out) {
    __shared__ float row[512];
    __shared__ float h1[256];
    __shared__ float h2[128];
    const int g = blockIdx.x;
    const int t = threadIdx.x;
    row[t] = outacc[g * 512 + t];
    row[256 + t] = outacc[g * 512 + 256 + t];
    __syncthreads();
    {
        float a = l1b[t];
        for (int j = 0; j < 512; ++j) a += row[j] * l1w[j * 256 + t];
        h1[t] = fmaxf(a, 0.f);
    }
    __syncthreads();
    if (t < 128) {
        float a2 = l2b[t];
        for (int j = 0; j < 256; ++j) a2 += h1[j] * l2w[j * 128 + t];
        h2[t] = fmaxf(a2, 0.f);
    }
    __syncthreads();
    if (t == 0) {
        float l0 = l3b[0], l1 = l3b[1];
        for (int j = 0; j < 128; ++j) {
            float h = h2[j];
            l0 += h * l3w[j * 2 + 0];
            l1 += h * l3w[j * 2 + 1];
        }
        float m = fmaxf(l0, l1);
        float lse = m + logf(expf(l0 - m) + expf(l1 - m));
        out[g * 2 + 0] = l0 - lse;
        out[g * 2 + 1] = l1 - lse;
    }
}

// ============================================================================
// Fallback: proven R15 monolith (used only if ws_size is too small)
// ============================================================================
__global__ __launch_bounds__(256, 1)
void gnn_mono(const float* __restrict__ x, const int* __restrict__ ei,
              const float* __restrict__ gw0, const float* __restrict__ gb0,
              const float* __restrict__ gw1, const float* __restrict__ gb1,
              const float* __restrict__ gw2, const float* __restrict__ gb2,
              const float* __restrict__ pw0, const float* __restrict__ pw1,
              const float* __restrict__ pw2,
              const float* __restrict__ l1w, const float* __restrict__ l1b,
              const float* __restrict__ l2w, const float* __restrict__ l2b,
              const float* __restrict__ l3w, const float* __restrict__ l3b,
              float* __restrict__ out, float* __restrict__ ws) {
    const int g = blockIdx.x;
    const int t = threadIdx.x;
    float* P = ws + (size_t)g * HF * 256;
    float* Q = ws + (size_t)G_GRAPHS * HF * 256 + (size_t)g * HF * 256;
    __shared__ int   eb[EPG];
    __shared__ int   slots[EPG];
    __shared__ int   curID[256];
    __shared__ int   cntL[256];
    __shared__ int   startL[256];
    __shared__ float degF[256];
    __shared__ float dinv[256];
    __shared__ float sa[256];
    __shared__ float ss[256];
    __shared__ int   si_[256];
    __shared__ float scoreV[256];
    __shared__ int   kept[128];
    __shared__ int   rankOf[256];
    __shared__ float row[512];
    for (int e = t; e < EPG; e += 256) {
        size_t idx = (size_t)g * EPG + e;
        eb[e] = ((ei[idx] - g * 256) << 8) | (ei[E_TOT + idx] - g * 256);
    }
    curID[t] = t;
    float accMx = 0.f, accMn = 0.f;
    const float* GW[3] = {gw0, gw1, gw2};
    const float* GB[3] = {gb0, gb1, gb2};
    const float* PW[3] = {pw0, pw1, pw2};
    const int kk[3] = {128, 64, 32};
    int npg = 256;
    __syncthreads();
    for (int s = 0; s < 3; ++s) {
        const int knext = kk[s];
        {
            const float* Wp = GW[s];
            const int K = (s == 0) ? FIN : HF;
            for (int n = 0; n < npg; ++n) {
                if (s == 0) { if (t < FIN) sa[t] = x[(size_t)(g * 256 + n) * FIN + t]; }
                else sa[t] = P[(size_t)n * HF + t];
                __syncthreads();
                float a = 0.f;
                for (int k2 = 0; k2 < K; ++k2) a += sa[k2] * Wp[k2 * HF + t];
                Q[(size_t)n * HF + t] = a;
                __syncthreads();
            }
        }
        cntL[t] = 0;
        __syncthreads();
        for (int e = t; e < EPG; e += 256) {
            int p = eb[e];
            int cu = curID[p >> 8], cv = curID[p & 255];
            if (cu >= 0 && cv >= 0) atomicAdd(&cntL[cv], 1);
        }
        __syncthreads();
        if (t == 0) { int run = 0; for (int i = 0; i < npg; ++i) { startL[i] = run; run += cntL[i]; } }
        __syncthreads();
        if (t < npg) {
            float d = (float)cntL[t] + 1.0f;
            degF[t] = d;
            dinv[t] = 1.0f / sqrtf(d);
            int c = startL[t];
            for (int e = 0; e < EPG; ++e) {
                int p = eb[e];
                int cu = curID[p >> 8], cv = curID[p & 255];
                if (cu >= 0 && cv >= 0 && cv == t) slots[c++] = e;
            }
        }
        __syncthreads();
        {
            const float bb = GB[s][t];
            for (int n = 0; n < npg; ++n) {
                float acc = 0.f;
                const int s0 = startL[n], s1 = s0 + cntL[n];
                for (int j = s0; j < s1; ++j) {
                    int scur = curID[eb[slots[j]] >> 8];
                    acc += dinv[scur] * Q[(size_t)scur * HF + t];
                }
                float v = acc * dinv[n] + Q[(size_t)n * HF + t] / degF[n] + bb;
                P[(size_t)n * HF + t] = fmaxf(v, 0.f);
            }
        }
        __syncthreads();
        {
            const float* pwp = PW[s];
            const int lane = t & 63, wv = t >> 6;
            float s2p = 0.f;
            for (int j = 0; j < 4; ++j) { float w = pwp[lane + 64 * j]; s2p += w * w; }
            for (int off = 32; off; off >>= 1) s2p += __shfl_down(s2p, off, 64);
            s2p = __shfl(s2p, 0, 64);
            const float nw = sqrtf(s2p);
            for (int n = wv; n < npg; n += 4) {
                float pr = 0.f;
                for (int j = 0; j < 4; ++j) { int f = lane + 64 * j; pr += P[(size_t)n * HF + f] * pwp[f]; }
                for (int off = 32; off; off >>= 1) pr += __shfl_down(pr, off, 64);
                if (lane == 0) scoreV[n] = tanhf(pr / nw);
            }
        }
        __syncthreads();
        if (t < npg) { ss[t] = scoreV[t]; si_[t] = t; }
        else         { ss[t] = -INFINITY; si_[t] = 0x7FFFFFFF; }
        for (int size = 2; size <= 256; size <<= 1) {
            for (int stride = size >> 1; stride > 0; stride >>= 1) {
                __syncthreads();
                int i = t, j = t ^ stride;
                if (j > i) {
                    float a = ss[i], b = ss[j];
                    int ia = si_[i], ib = si_[j];
                    bool inOrder = (a > b) || (a == b && ia < ib);
                    bool desc = ((i & size) == 0);
                    if (desc ? !inOrder : inOrder) { ss[i] = b; ss[j] = a; si_[i] = ib; si_[j] = ia; }
                }
            }
        }
        __syncthreads();
        if (t < knext) kept[t] = si_[t];
        __syncthreads();
        {
            float mx = -INFINITY, sm = 0.f;
            for (int n = 0; n < knext; ++n) {
                int o = kept[n];
                float vv = P[(size_t)o * HF + t] * scoreV[o];
                Q[(size_t)n * HF + t] = vv;
                mx = fmaxf(mx, vv);
                sm += vv;
            }
            accMx += mx;
            accMn += sm / (float)knext;
        }
        rankOf[t] = -1;
        __syncthreads();
        if (t < knext) rankOf[kept[t]] = t;
        __syncthreads();
        { int c = curID[t]; curID[t] = (c >= 0) ? rankOf[c] : -1; }
        __syncthreads();
        { float* tmp = P; P = Q; Q = tmp; }
        npg = knext;
    }
    row[t] = accMx;
    row[256 + t] = accMn;
    __syncthreads();
    { float a = l1b[t]; for (int j = 0; j < 512; ++j) a += row[j] * l1w[j * 256 + t]; scoreV[t] = fmaxf(a, 0.f); }
    __syncthreads();
    if (t < 128) { float a2 = l2b[t]; for (int j = 0; j < 256; ++j) a2 += scoreV[j] * l2w[j * 128 + t]; sa[t] = fmaxf(a2, 0.f); }
    __syncthreads();
    if (t == 0) {
        float l0 = l3b[0], l1 = l3b[1];
        for (int j = 0; j < 128; ++j) { float h = sa[j]; l0 += h * l3w[j * 2 + 0]; l1 += h * l3w[j * 2 + 1]; }
        float m = fmaxf(l0, l1);
        float lse = m + logf(expf(l0 - m) + expf(l1 - m));
        out[g * 2 + 0] = l0 - lse;
        out[g * 2 + 1] = l1 - lse;
    }
}

// ============================================================================
extern "C" void kernel_launch(void* const* d_in, const int* in_sizes, int n_in,
                              void* d_out, int out_size, void* d_ws, size_t ws_size,
                              hipStream_t stream) {
    const float* x   = (const float*)d_in[0];
    const int*   ei  = (const int*)d_in[1];
    const float* gw0 = (const float*)d_in[3];
    const float* gb0 = (const float*)d_in[4];
    const float* gw1 = (const float*)d_in[5];
    const float* gb1 = (const float*)d_in[6];
    const float* gw2 = (const float*)d_in[7];
    const float* gb2 = (const float*)d_in[8];
    const float* pw0 = (const float*)d_in[9];
    const float* pw1 = (const float*)d_in[10];
    const float* pw2 = (const float*)d_in[11];
    const float* l1w = (const float*)d_in[12];
    const float* l1b = (const float*)d_in[13];
    const float* l2w = (const float*)d_in[14];
    const float* l2b = (const float*)d_in[15];
    const float* l3w = (const float*)d_in[16];
    const float* l3b = (const float*)d_in[17];
    float* out = (float*)d_out;

    // ---- workspace carve ----
    const size_t SLAB = (size_t)65536 * 256;        // floats
    char* p = (char*)d_ws;
    float* P      = (float*)p; p += SLAB * 4;       // 64 MB
    float* Q      = (float*)p; p += SLAB * 4;       // 64 MB
    int*   cur    = (int*)p;   p += (size_t)65536 * 4;
    int*   degS   = (int*)p;   p += (size_t)65536 * 4;
    float* dinvS  = (float*)p; p += (size_t)65536 * 4;
    int*   starts = (int*)p;   p += (size_t)65536 * 4;
    int*   slotsS = (int*)p;   p += (size_t)E_TOT * 4;
    float* score  = (float*)p; p += (size_t)65536 * 4;
    int*   kept   = (int*)p;   p += (size_t)32768 * 4;
    float* outacc = (float*)p; p += (size_t)G_GRAPHS * 512 * 4;
    const size_t needed = (size_t)(p - (char*)d_ws);

    if (ws_size < needed) {
        // fallback: proven monolith (needs only 128 MB)
        gnn_mono<<<G_GRAPHS, 256, 0, stream>>>(
            x, ei, gw0, gb0, gw1, gb1, gw2, gb2, pw0, pw1, pw2,
            l1w, l1b, l2w, l2b, l3w, l3b, out, (float*)d_ws);
        return;
    }

    init_cur<<<(G_GRAPHS * 256 + 255) / 256, 256, 0, stream>>>(cur);

    const int   npg[3] = {256, 128, 64};
    const int   kk[3]  = {128, 64, 32};
    const int   Ns[3]  = {65536, 32768, 16384};
    const float* GW[3] = {gw0, gw1, gw2};
    const float* GB[3] = {gb0, gb1, gb2};
    const float* PW[3] = {pw0, pw1, pw2};

    // slab roles per stage: (in, HL, H2, pooled)
    // s0: x -> P(HL); agg P->Q(H2); pool Q->P(pooled)
    // s1: P -> Q(HL); agg Q->P(H2); pool P->Q
    // s2: Q -> P(HL); agg P->Q(H2); pool Q->P
    float* HLs[3]   = {P, Q, P};
    float* H2s[3]   = {Q, P, Q};
    float* POOLs[3] = {P, Q, P};

    for (int s = 0; s < 3; ++s) {
        const int n = Ns[s];
        const int k = kk[s];
        // 1) GEMM
        if (s == 0) {
            dim3 grid(n / 64, 4);
            gemm_t4<FIN><<<grid, 256, 0, stream>>>(x, GW[s], HLs[s]);
        } else {
            dim3 grid(n / 64, 4);
            gemm_t4<HF><<<grid, 256, 0, stream>>>(POOLs[s - 1], GW[s], HLs[s]);
        }
        // 2) CSR
        csr_build<<<G_GRAPHS, 256, 0, stream>>>(ei, cur, npg[s],
                                                degS, dinvS, starts, slotsS);
        // 3) conv + score
        agg_score<<<n, 256, 0, stream>>>(degS, dinvS, starts, slotsS,
                                         HLs[s], H2s[s], GB[s], PW[s], score);
        // 4) top-k + cur update
        topk_cur<<<G_GRAPHS, 256, 0, stream>>>(score, npg[s], k, kept, cur);
        // 5) pool
        pool_gather<<<G_GRAPHS * k, 256, 0, stream>>>(kept, score, H2s[s], POOLs[s]);
        // 6) readout
        readout<<<G_GRAPHS, 256, 0, stream>>>(POOLs[s], k, outacc, s == 0 ? 1 : 0);
    }

    mlp_head<<<G_GRAPHS, 256, 0, stream>>>(outacc, l1w, l1b, l2w, l2b, l3w, l3b, out);
}